// Round 1
// baseline (19320.328 us; speedup 1.0000x reference)
//
#include <hip/hip_runtime.h>
#include <math.h>
#include <limits.h>

#define B32 32
#define KD 1024
#define HID 1024
#define VOC 32000
#define NL 3
#define TN 128
#define BKC 32
#define ASTR 36
#define WSTR 68
#define GEMM_THREADS 128
#define KS_GRU 4

__device__ __forceinline__ float sigmoidf_(float x) { return 1.0f / (1.0f + expf(-x)); }

// Generic C = A[32xK=1024] @ W[NxK]^T (+bias), k-split partials.
// grid.x = (N/TN)*KS, grid.y = nsel (1 or 2). sel=0 uses (Ax or emb-gather, Wx); sel=1 uses (Ah, Wh).
// C layout: [nsel*KS][32][N], slice = sel*KS + ks. bias added only when ks==0 && bias != nullptr.
__global__ __launch_bounds__(GEMM_THREADS)
void gemm_k1024(const float* __restrict__ Ax, const float* __restrict__ Ah,
                const float* __restrict__ emb, const int* __restrict__ tokens, int gather0,
                const float* __restrict__ Wx, const float* __restrict__ Wh,
                const float* __restrict__ bias,
                float* __restrict__ C, int N, int KS)
{
    __shared__ float As[BKC * ASTR];
    __shared__ float Ws[2 * BKC * WSTR];
    const int tid = threadIdx.x;
    const int sel = blockIdx.y;
    const int ks  = blockIdx.x % KS;
    const int nt  = blockIdx.x / KS;
    const int n0  = nt * TN;
    const int klen = KD / KS;
    const int k0 = ks * klen;
    const float* A = sel ? Ah : Ax;
    const float* W = sel ? Wh : Wx;
    const bool gather = (sel == 0) && (gather0 != 0);

    const int tb = tid & 7;    // b-group: rows 4*tb..4*tb+3
    const int tn = tid >> 3;   // n-group: cols n0+4*tn..+3 and n0+64+4*tn..+3
    const int s_kq = tid & 7;  // 16B unit within 128B k-chunk
    const int s_r  = tid >> 3; // 0..15

    const float* arow0;
    const float* arow1;
    if (gather) {
        arow0 = emb + (size_t)tokens[s_r] * KD;
        arow1 = emb + (size_t)tokens[s_r + 16] * KD;
    } else {
        arow0 = A + (size_t)s_r * KD;
        arow1 = A + (size_t)(s_r + 16) * KD;
    }
    const float* wrow = W + (size_t)(n0 + s_r) * KD;

    float acc[4][8];
#pragma unroll
    for (int i = 0; i < 4; ++i)
#pragma unroll
        for (int j = 0; j < 8; ++j) acc[i][j] = 0.0f;

    for (int kc = 0; kc < klen; kc += BKC) {
        const int kb = k0 + kc + s_kq * 4;
        float4 a0 = *(const float4*)(arow0 + kb);
        float4 a1 = *(const float4*)(arow1 + kb);
        float4 wv[8];
#pragma unroll
        for (int hh = 0; hh < 8; ++hh)
            wv[hh] = *(const float4*)(wrow + (size_t)hh * 16 * KD + kb);

        __syncthreads();   // protect previous iteration's LDS reads
#pragma unroll
        for (int j = 0; j < 4; ++j) {
            As[(s_kq * 4 + j) * ASTR + s_r]      = ((const float*)&a0)[j];
            As[(s_kq * 4 + j) * ASTR + s_r + 16] = ((const float*)&a1)[j];
        }
#pragma unroll
        for (int hh = 0; hh < 8; ++hh) {
            int row = s_r + hh * 16;       // 0..127
            int half = row >> 6;
            int c = row & 63;
            float* wbase = &Ws[half * BKC * WSTR];
#pragma unroll
            for (int j = 0; j < 4; ++j)
                wbase[(s_kq * 4 + j) * WSTR + c] = ((const float*)&wv[hh])[j];
        }
        __syncthreads();

#pragma unroll
        for (int kk = 0; kk < BKC; ++kk) {
            float4 av = *(const float4*)&As[kk * ASTR + 4 * tb];
            float4 w0 = *(const float4*)&Ws[kk * WSTR + 4 * tn];
            float4 w1 = *(const float4*)&Ws[BKC * WSTR + kk * WSTR + 4 * tn];
#pragma unroll
            for (int i = 0; i < 4; ++i) {
                float a = ((const float*)&av)[i];
                acc[i][0] += a * w0.x; acc[i][1] += a * w0.y;
                acc[i][2] += a * w0.z; acc[i][3] += a * w0.w;
                acc[i][4] += a * w1.x; acc[i][5] += a * w1.y;
                acc[i][6] += a * w1.z; acc[i][7] += a * w1.w;
            }
        }
    }

    const int slice = sel * KS + ks;
    float* Cb = C + (size_t)slice * B32 * N;
    float4 bA = make_float4(0.f, 0.f, 0.f, 0.f), bB = bA;
    if (bias != nullptr && ks == 0) {
        bA = *(const float4*)&bias[n0 + 4 * tn];
        bB = *(const float4*)&bias[n0 + 64 + 4 * tn];
    }
#pragma unroll
    for (int i = 0; i < 4; ++i) {
        int b = 4 * tb + i;
        float4 vA = make_float4(acc[i][0] + bA.x, acc[i][1] + bA.y, acc[i][2] + bA.z, acc[i][3] + bA.w);
        float4 vB = make_float4(acc[i][4] + bB.x, acc[i][5] + bB.y, acc[i][6] + bB.z, acc[i][7] + bB.w);
        *(float4*)&Cb[(size_t)b * N + n0 + 4 * tn]       = vA;
        *(float4*)&Cb[(size_t)b * N + n0 + 64 + 4 * tn]  = vB;
    }
}

// h[l] update from G = [2*KS][32][3072] partials (gx slices 0..KS-1, gh slices KS..2KS-1)
__global__ __launch_bounds__(256)
void gru_gates(const float* __restrict__ G,
               const float* __restrict__ bih, const float* __restrict__ bhh,
               float* __restrict__ hl)
{
    int idx = blockIdx.x * 256 + threadIdx.x;  // < 32768
    int b = idx >> 10, j = idx & 1023;
    float xr = 0, xz = 0, xn = 0, hr = 0, hz = 0, hn = 0;
#pragma unroll
    for (int ks = 0; ks < KS_GRU; ++ks) {
        const float* gx = G + ((size_t)ks * B32 + b) * 3072;
        const float* gh = G + ((size_t)(KS_GRU + ks) * B32 + b) * 3072;
        xr += gx[j];        xz += gx[1024 + j];  xn += gx[2048 + j];
        hr += gh[j];        hz += gh[1024 + j];  hn += gh[2048 + j];
    }
    float r = sigmoidf_(xr + bih[j] + hr + bhh[j]);
    float z = sigmoidf_(xz + bih[1024 + j] + hz + bhh[1024 + j]);
    float n = tanhf(xn + bih[2048 + j] + r * (hn + bhh[2048 + j]));
    float ho = hl[idx];
    hl[idx] = (1.0f - z) * n + z * ho;
}

// logits = x[32x1024] @ fc_w^T + fc_b ; writes out[b][t][:] and per-block argmax partials
__global__ __launch_bounds__(GEMM_THREADS)
void logits_kernel(const float* __restrict__ x,
                   const float* __restrict__ W, const float* __restrict__ bias,
                   float* __restrict__ out, int t, int T,
                   float* __restrict__ pval, int* __restrict__ pidx)
{
    __shared__ float As[BKC * ASTR];
    __shared__ float Ws[2 * BKC * WSTR];
    __shared__ float rval[B32 * 16];
    __shared__ int   ridx[B32 * 16];
    const int tid = threadIdx.x;
    const int n0 = blockIdx.x * TN;
    const int tb = tid & 7;
    const int tn = tid >> 3;
    const int s_kq = tid & 7;
    const int s_r  = tid >> 3;

    const float* arow0 = x + (size_t)s_r * KD;
    const float* arow1 = x + (size_t)(s_r + 16) * KD;
    const float* wrow  = W + (size_t)(n0 + s_r) * KD;

    float acc[4][8];
#pragma unroll
    for (int i = 0; i < 4; ++i)
#pragma unroll
        for (int j = 0; j < 8; ++j) acc[i][j] = 0.0f;

    for (int kc = 0; kc < KD; kc += BKC) {
        const int kb = kc + s_kq * 4;
        float4 a0 = *(const float4*)(arow0 + kb);
        float4 a1 = *(const float4*)(arow1 + kb);
        float4 wv[8];
#pragma unroll
        for (int hh = 0; hh < 8; ++hh)
            wv[hh] = *(const float4*)(wrow + (size_t)hh * 16 * KD + kb);

        __syncthreads();
#pragma unroll
        for (int j = 0; j < 4; ++j) {
            As[(s_kq * 4 + j) * ASTR + s_r]      = ((const float*)&a0)[j];
            As[(s_kq * 4 + j) * ASTR + s_r + 16] = ((const float*)&a1)[j];
        }
#pragma unroll
        for (int hh = 0; hh < 8; ++hh) {
            int row = s_r + hh * 16;
            int half = row >> 6;
            int c = row & 63;
            float* wbase = &Ws[half * BKC * WSTR];
#pragma unroll
            for (int j = 0; j < 4; ++j)
                wbase[(s_kq * 4 + j) * WSTR + c] = ((const float*)&wv[hh])[j];
        }
        __syncthreads();

#pragma unroll
        for (int kk = 0; kk < BKC; ++kk) {
            float4 av = *(const float4*)&As[kk * ASTR + 4 * tb];
            float4 w0 = *(const float4*)&Ws[kk * WSTR + 4 * tn];
            float4 w1 = *(const float4*)&Ws[BKC * WSTR + kk * WSTR + 4 * tn];
#pragma unroll
            for (int i = 0; i < 4; ++i) {
                float a = ((const float*)&av)[i];
                acc[i][0] += a * w0.x; acc[i][1] += a * w0.y;
                acc[i][2] += a * w0.z; acc[i][3] += a * w0.w;
                acc[i][4] += a * w1.x; acc[i][5] += a * w1.y;
                acc[i][6] += a * w1.z; acc[i][7] += a * w1.w;
            }
        }
    }

    float4 bA = *(const float4*)&bias[n0 + 4 * tn];
    float4 bB = *(const float4*)&bias[n0 + 64 + 4 * tn];

    float bestv[4]; int besti[4];
#pragma unroll
    for (int i = 0; i < 4; ++i) { bestv[i] = -INFINITY; besti[i] = INT_MAX; }

#pragma unroll
    for (int i = 0; i < 4; ++i) {
        int b = 4 * tb + i;
        float* orow = out + ((size_t)b * T + t) * VOC;
        float4 vA = make_float4(acc[i][0] + bA.x, acc[i][1] + bA.y, acc[i][2] + bA.z, acc[i][3] + bA.w);
        float4 vB = make_float4(acc[i][4] + bB.x, acc[i][5] + bB.y, acc[i][6] + bB.z, acc[i][7] + bB.w);
        *(float4*)&orow[n0 + 4 * tn]      = vA;
        *(float4*)&orow[n0 + 64 + 4 * tn] = vB;
#pragma unroll
        for (int j = 0; j < 4; ++j) {
            float v = ((const float*)&vA)[j]; int c = n0 + 4 * tn + j;
            if (v > bestv[i] || (v == bestv[i] && c < besti[i])) { bestv[i] = v; besti[i] = c; }
        }
#pragma unroll
        for (int j = 0; j < 4; ++j) {
            float v = ((const float*)&vB)[j]; int c = n0 + 64 + 4 * tn + j;
            if (v > bestv[i] || (v == bestv[i] && c < besti[i])) { bestv[i] = v; besti[i] = c; }
        }
    }
#pragma unroll
    for (int i = 0; i < 4; ++i) {
        rval[(4 * tb + i) * 16 + tn] = bestv[i];
        ridx[(4 * tb + i) * 16 + tn] = besti[i];
    }
    __syncthreads();
    if (tid < B32) {
        int b = tid;
        float bv = -INFINITY; int bi = INT_MAX;
        for (int q = 0; q < 16; ++q) {
            float v = rval[b * 16 + q]; int ii = ridx[b * 16 + q];
            if (v > bv || (v == bv && ii < bi)) { bv = v; bi = ii; }
        }
        pval[(size_t)blockIdx.x * B32 + b] = bv;
        pidx[(size_t)blockIdx.x * B32 + b] = bi;
    }
}

__global__ __launch_bounds__(256)
void amax_final(const float* __restrict__ pval, const int* __restrict__ pidx,
                int nblk, int* __restrict__ tokens)
{
    int tid = threadIdx.x;
    int b = tid >> 3, l8 = tid & 7;
    float bv = -INFINITY; int bi = INT_MAX;
    for (int q = l8; q < nblk; q += 8) {
        float v = pval[(size_t)q * B32 + b]; int ii = pidx[(size_t)q * B32 + b];
        if (v > bv || (v == bv && ii < bi)) { bv = v; bi = ii; }
    }
#pragma unroll
    for (int off = 1; off < 8; off <<= 1) {
        float ov = __shfl_xor(bv, off);
        int   oi = __shfl_xor(bi, off);
        if (ov > bv || (ov == bv && oi < bi)) { bv = ov; bi = oi; }
    }
    if (l8 == 0) tokens[b] = bi;
}

extern "C" void kernel_launch(void* const* d_in, const int* in_sizes, int n_in,
                              void* d_out, int out_size, void* d_ws, size_t ws_size,
                              hipStream_t stream)
{
    const float* z    = (const float*)d_in[0];
    const float* emb  = (const float*)d_in[1];
    const float* wlat = (const float*)d_in[2];
    const float* blat = (const float*)d_in[3];
    const float* wih  = (const float*)d_in[4];
    const float* whh  = (const float*)d_in[5];
    const float* bih  = (const float*)d_in[6];
    const float* bhh  = (const float*)d_in[7];
    const float* fcw  = (const float*)d_in[8];
    const float* fcb  = (const float*)d_in[9];
    float* out = (float*)d_out;
    const int T = out_size / (B32 * VOC);   // 128

    float* h      = (float*)d_ws;                          // [32][3072] == [3][32][1024] flat
    float* G      = h + (size_t)B32 * NL * HID;            // [2*KS][32][3072]
    float* pval   = G + (size_t)2 * KS_GRU * B32 * NL * HID;
    int*   pidx   = (int*)(pval + (VOC / TN) * B32);
    int*   tokens = (int*)(pidx + (VOC / TN) * B32);

    hipMemsetAsync(tokens, 0, B32 * sizeof(int), stream);

    // init hidden = z @ w_lat^T + b_lat  (flat reinterpretation handles the reshape(L,B,H))
    {
        dim3 gi(NL * HID / TN, 1);   // (24, 1)
        gemm_k1024<<<gi, GEMM_THREADS, 0, stream>>>(z, nullptr, nullptr, nullptr, 0,
                                                    wlat, nullptr, blat, h, NL * HID, 1);
    }

    for (int t = 0; t < T; ++t) {
        for (int l = 0; l < NL; ++l) {
            const float* xA = (l == 0) ? nullptr : (h + (size_t)(l - 1) * B32 * HID);
            dim3 gg((NL * HID / TN) * KS_GRU, 2);    // (96, 2)
            gemm_k1024<<<gg, GEMM_THREADS, 0, stream>>>(
                xA, h + (size_t)l * B32 * HID, emb, tokens, (l == 0) ? 1 : 0,
                wih + (size_t)l * NL * HID * KD, whh + (size_t)l * NL * HID * KD,
                nullptr, G, NL * HID, KS_GRU);
            gru_gates<<<B32 * HID / 256, 256, 0, stream>>>(
                G, bih + (size_t)l * NL * HID, bhh + (size_t)l * NL * HID,
                h + (size_t)l * B32 * HID);
        }
        logits_kernel<<<VOC / TN, GEMM_THREADS, 0, stream>>>(
            h + (size_t)2 * B32 * HID, fcw, fcb, out, t, T, pval, pidx);
        amax_final<<<1, 256, 0, stream>>>(pval, pidx, VOC / TN, tokens);
    }
}